// Round 2
// baseline (4262.736 us; speedup 1.0000x reference)
//
#include <hip/hip_runtime.h>
#include <math.h>

typedef unsigned short u16;
typedef __bf16 bf16x8 __attribute__((ext_vector_type(8)));
typedef float f32x4 __attribute__((ext_vector_type(4)));
typedef unsigned long long u64;

__device__ __forceinline__ float bf2f(u16 u) {
    union { unsigned u32; float f; } c; c.u32 = ((unsigned)u) << 16; return c.f;
}
__device__ __forceinline__ u16 f2bf(float f) {
    unsigned u = __float_as_uint(f);
    unsigned r = u + 0x7fff + ((u >> 16) & 1);
    return (u16)(r >> 16);
}
// element i of a float tensor whose dtype (bf16 vs fp32) is runtime-detected
__device__ __forceinline__ float ldmix(const void* p, u64 i, int isbf) {
    return isbf ? bf2f(((const u16*)p)[i]) : ((const float*)p)[i];
}
// async global->LDS, 16B per lane. LDS dest is wave-uniform base + lane*16.
__device__ __forceinline__ void gll16(const u16* g, u16* l) {
    __builtin_amdgcn_global_load_lds(
        (const __attribute__((address_space(1))) void*)g,
        (__attribute__((address_space(3))) void*)l, 16, 0, 0);
}

// ---------------------------------------------------------------------------
// Dtype probe: sample 64 words of tok_emb (nonzero rows). If low-16 bits look
// like bf16 N(0,0.02) values (exp field in [100,126]) for >=40/64 lanes,
// inputs are bf16. fp32 mantissa bits hit that window only ~10% of the time.
// ---------------------------------------------------------------------------
__global__ void detect_kernel(const unsigned* __restrict__ tokw, int* __restrict__ flag)
{
    int i = threadIdx.x;  // 0..63
    unsigned w = tokw[768 + i];
    unsigned e = (w >> 7) & 0xFF;
    bool hit = (e >= 100) && (e <= 126) && ((w & 0x7FFFu) != 0);
    unsigned long long m = __ballot(hit);
    if (i == 0) flag[0] = (__popcll(m) >= 40) ? 1 : 0;
}

// ---------------------------------------------------------------------------
// Embedding: h = tok_emb[x] + seg_emb[segment] + PE (computed on device)
// Writes fp32 (residual path) AND bf16 (GEMM-A path).
// ---------------------------------------------------------------------------
__global__ __launch_bounds__(256) void embed_kernel(
    const int* __restrict__ x, const int* __restrict__ seg,
    const void* __restrict__ tok, const void* __restrict__ se,
    const int* __restrict__ flagp, float* __restrict__ hF, u16* __restrict__ hB)
{
    int isbf = *flagp;
    int t = blockIdx.x;
    int pos = t & 63;
    int tokid = x[t], sgid = seg[t];
    int tid = threadIdx.x;
#pragma unroll
    for (int i = 0; i < 3; i++) {
        int d = tid + i * 256;
        int p = d >> 1;
        float freq = powf(10000.0f, (float)p * (1.0f / 192.0f));
        float arg = (float)pos / freq;
        float pe = (d & 1) ? cosf(arg) : sinf(arg);
        float v = ldmix(tok, (u64)tokid * 768 + d, isbf)
                + ldmix(se, (u64)sgid * 768 + d, isbf) + pe;
        hF[(u64)t * 768 + d] = v;
        hB[(u64)t * 768 + d] = f2bf(v);
    }
}

// ---------------------------------------------------------------------------
// Transpose+stage layer l's 6 weight matrices to bf16 [N][K] layout.
// ---------------------------------------------------------------------------
__global__ __launch_bounds__(256) void transpose6(
    const void* __restrict__ wq, const void* __restrict__ wk,
    const void* __restrict__ wv, const void* __restrict__ wo,
    const void* __restrict__ w1, const void* __restrict__ w2,
    u16* __restrict__ out, const int* __restrict__ flagp, u64 oS, u64 oF)
{
    int isbf = *flagp;
    int id = blockIdx.x;
    const void* src; u16* dst; int R, C; u64 off;
    if (id < 2304) {
        int m = id / 576; id -= m * 576; R = 768; C = 768; off = oS;
        src = (m == 0) ? wq : (m == 1) ? wk : (m == 2) ? wv : wo;
        dst = out + (u64)m * 589824;
    } else if (id < 4608) {
        id -= 2304; R = 768; C = 3072; off = oF; src = w1; dst = out + 2359296;
    } else {
        id -= 4608; R = 3072; C = 768; off = oF; src = w2; dst = out + 4718592;
    }
    int tilesC = C >> 5;
    int tr = id / tilesC, tc = id % tilesC;
    __shared__ float tile[32][33];
    int rl = threadIdx.x >> 5, cl = threadIdx.x & 31;
#pragma unroll
    for (int i = 0; i < 4; i++)
        tile[rl + 8 * i][cl] = ldmix(src, off + (u64)(tr * 32 + rl + 8 * i) * C + tc * 32 + cl, isbf);
    __syncthreads();
#pragma unroll
    for (int i = 0; i < 4; i++)
        dst[(u64)(tc * 32 + rl + 8 * i) * R + tr * 32 + cl] = f2bf(tile[cl][rl + 8 * i]);
}

// ---------------------------------------------------------------------------
// 256x256 8-phase bf16 MFMA GEMM (m201 structure): C = A[M,K] @ Bt[N,K]^T.
// 512 thr = 8 waves (2M x 4N), per-wave 128x64 out, BK=64 (2 kk-halves).
// LDS 128KB: 2 slots x {A-kk0,A-kk1,B-kk0,B-kk1} 16KB regions.
// Each phase: ds_read frags | stage 1 half-tile (2x global_load_lds) |
//   barrier | lgkmcnt(0) | setprio(1) 16 MFMA setprio(0) | [vmcnt] barrier.
// vmcnt(6) once per K-tile (3 half-tiles stay in flight); tail uses vmcnt(0).
// Read swizzle: 16B-chunk q -> q ^ ((row>>1)&3); inverse applied to global
// source addr during staging (LDS dest stays linear for global_load_lds).
// MODE 1: outF = acc+bias+resid (fp32) | 2: outB = gelu(acc+bias) (bf16)
// MODE 3: fused QKV - bias from {bA,bB,bC} by 256-col tile (bf16 out)
// ---------------------------------------------------------------------------
template <int MODE>
__global__ __launch_bounds__(512, 2) void gemm8p(
    const u16* __restrict__ A, const u16* __restrict__ Bt,
    const void* __restrict__ bA, const void* __restrict__ bB,
    const void* __restrict__ bC, u64 oB, const float* __restrict__ resid,
    float* __restrict__ outF, u16* __restrict__ outB,
    const int* __restrict__ flagp, int N, int K)
{
    __shared__ __align__(16) u16 sm[65536];   // 128 KB
    const int NT = K >> 6;
    int tid = threadIdx.x;
    int lane = tid & 63, wave = tid >> 6;
    int wr = wave >> 2, wc = wave & 3;        // 2 x 4 wave grid
    int cl = lane & 15, quad = lane >> 4;
    int bn = blockIdx.x, bm = blockIdx.y;

    // read-side per-thread LDS offsets (u16 units), bank-swizzled
    int offA[8], offB[4];
#pragma unroll
    for (int mi = 0; mi < 8; mi++) {
        int r = wr * 128 + mi * 16 + cl;
        offA[mi] = r * 32 + ((quad ^ ((r >> 1) & 3)) << 3);
    }
#pragma unroll
    for (int ni = 0; ni < 4; ni++) {
        int r = wc * 64 + ni * 16 + cl;
        offB[ni] = r * 32 + ((quad ^ ((r >> 1) & 3)) << 3);
    }

    // stage-side: per-thread global sources (inverse swizzle), 2 chunks/thread
    const u16 *sA0, *sA1, *sB0, *sB1;
    const int dst0 = wave * 512;          // u16 offset of wave's chunk run, j=0
    const int dst1 = 4096 + wave * 512;   // j=1
    {
        int c0 = wave * 64 + lane, c1 = 512 + wave * 64 + lane;
        int r0 = c0 >> 2, q0 = (c0 & 3) ^ ((r0 >> 1) & 3);
        int r1 = c1 >> 2, q1 = (c1 & 3) ^ ((r1 >> 1) & 3);
        sA0 = A  + (u64)(bm * 256 + r0) * K + q0 * 8;
        sA1 = A  + (u64)(bm * 256 + r1) * K + q1 * 8;
        sB0 = Bt + (u64)(bn * 256 + r0) * K + q0 * 8;
        sB1 = Bt + (u64)(bn * 256 + r1) * K + q1 * 8;
    }
    // LDS region offsets (u16): slot*32768 + {A-kk0:0, A-kk1:8192, B-kk0:16384, B-kk1:24576}
    auto STG = [&](int ro, const u16* a0, const u16* a1, int koff) {
        gll16(a0 + koff, sm + ro + dst0);
        gll16(a1 + koff, sm + ro + dst1);
    };

    f32x4 acc[8][4];
    const f32x4 vz = {0.f, 0.f, 0.f, 0.f};
#pragma unroll
    for (int mi = 0; mi < 8; mi++)
#pragma unroll
        for (int ni = 0; ni < 4; ni++) acc[mi][ni] = vz;

    // prologue: tile0 all 4 halves, tile1 {A-kk0,B-kk0,B-kk1} (A-kk1(1) at t=0 ph0)
    STG(0,     sA0, sA1, 0);
    STG(16384, sB0, sB1, 0);
    STG(8192,  sA0, sA1, 32);
    STG(24576, sB0, sB1, 32);
    if (NT > 1) {
        STG(32768,         sA0, sA1, 64);
        STG(32768 + 16384, sB0, sB1, 64);
        STG(32768 + 24576, sB0, sB1, 96);
        asm volatile("s_waitcnt vmcnt(6)" ::: "memory");
    } else {
        asm volatile("s_waitcnt vmcnt(0)" ::: "memory");
    }
    __builtin_amdgcn_s_barrier();

    for (int t = 0; t < NT; t++) {
        const int sl = (t & 1) * 32768;
        const int osl = sl ^ 32768;
        const u16* Ak0 = sm + sl;
        const u16* Ak1 = sm + sl + 8192;
        const u16* Bk0 = sm + sl + 16384;
        const u16* Bk1 = sm + sl + 24576;
        const int k1 = (t + 1) * 64, k2 = (t + 2) * 64;
        bf16x8 af[4], bf[4];

        // ---- phase 0: kk0, mi 0-3 (+ B kk0); stage A-kk1(t+1)
#pragma unroll
        for (int i = 0; i < 4; i++) af[i] = *(const bf16x8*)(Ak0 + offA[i]);
#pragma unroll
        for (int i = 0; i < 4; i++) bf[i] = *(const bf16x8*)(Bk0 + offB[i]);
        if (t + 1 < NT) STG(osl + 8192, sA0, sA1, k1 + 32);
        __builtin_amdgcn_s_barrier();
        asm volatile("s_waitcnt lgkmcnt(0)" ::: "memory");
        __builtin_amdgcn_s_setprio(1);
#pragma unroll
        for (int mi = 0; mi < 4; mi++)
#pragma unroll
            for (int ni = 0; ni < 4; ni++)
                acc[mi][ni] = __builtin_amdgcn_mfma_f32_16x16x32_bf16(
                    af[mi], bf[ni], acc[mi][ni], 0, 0, 0);
        __builtin_amdgcn_s_setprio(0);
        __builtin_amdgcn_s_barrier();

        // ---- phase 1: kk0, mi 4-7; stage B-kk0(t+2)
#pragma unroll
        for (int i = 0; i < 4; i++) af[i] = *(const bf16x8*)(Ak0 + offA[4 + i]);
        if (t + 2 < NT) STG(sl + 16384, sB0, sB1, k2);
        __builtin_amdgcn_s_barrier();
        asm volatile("s_waitcnt lgkmcnt(0)" ::: "memory");
        __builtin_amdgcn_s_setprio(1);
#pragma unroll
        for (int mi = 0; mi < 4; mi++)
#pragma unroll
            for (int ni = 0; ni < 4; ni++)
                acc[4 + mi][ni] = __builtin_amdgcn_mfma_f32_16x16x32_bf16(
                    af[mi], bf[ni], acc[4 + mi][ni], 0, 0, 0);
        __builtin_amdgcn_s_setprio(0);
        __builtin_amdgcn_s_barrier();

        // ---- phase 2: kk1, mi 0-3 (+ B kk1); stage A-kk0(t+2)
#pragma unroll
        for (int i = 0; i < 4; i++) af[i] = *(const bf16x8*)(Ak1 + offA[i]);
#pragma unroll
        for (int i = 0; i < 4; i++) bf[i] = *(const bf16x8*)(Bk1 + offB[i]);
        if (t + 2 < NT) STG(sl, sA0, sA1, k2);
        __builtin_amdgcn_s_barrier();
        asm volatile("s_waitcnt lgkmcnt(0)" ::: "memory");
        __builtin_amdgcn_s_setprio(1);
#pragma unroll
        for (int mi = 0; mi < 4; mi++)
#pragma unroll
            for (int ni = 0; ni < 4; ni++)
                acc[mi][ni] = __builtin_amdgcn_mfma_f32_16x16x32_bf16(
                    af[mi], bf[ni], acc[mi][ni], 0, 0, 0);
        __builtin_amdgcn_s_setprio(0);
        __builtin_amdgcn_s_barrier();

        // ---- phase 3: kk1, mi 4-7; stage B-kk1(t+2); per-tile vmcnt
#pragma unroll
        for (int i = 0; i < 4; i++) af[i] = *(const bf16x8*)(Ak1 + offA[4 + i]);
        if (t + 2 < NT) STG(sl + 24576, sB0, sB1, k2 + 32);
        __builtin_amdgcn_s_barrier();
        asm volatile("s_waitcnt lgkmcnt(0)" ::: "memory");
        __builtin_amdgcn_s_setprio(1);
#pragma unroll
        for (int mi = 0; mi < 4; mi++)
#pragma unroll
            for (int ni = 0; ni < 4; ni++)
                acc[4 + mi][ni] = __builtin_amdgcn_mfma_f32_16x16x32_bf16(
                    af[mi], bf[ni], acc[4 + mi][ni], 0, 0, 0);
        __builtin_amdgcn_s_setprio(0);
        if (t + 2 < NT) asm volatile("s_waitcnt vmcnt(6)" ::: "memory");
        else            asm volatile("s_waitcnt vmcnt(0)" ::: "memory");
        __builtin_amdgcn_s_barrier();
    }

    int isbf = *flagp;
    int rowb = bm * 256 + wr * 128 + quad * 4;   // C/D: col=lane&15, row=quad*4+reg
    int colb = bn * 256 + wc * 64 + cl;
    const void* bp = bA;
    int csub = 0;
    if (MODE == 3) {       // 9 col-tiles of 256: 0-2 Q, 3-5 K, 6-8 V
        int ms = bn / 3;
        bp = (ms == 0) ? bA : (ms == 1) ? bB : bC;
        csub = ms * 768;
    }
#pragma unroll
    for (int ni = 0; ni < 4; ni++) {
        int col = colb + ni * 16;
        float bv = ldmix(bp, oB + (u64)(col - csub), isbf);
#pragma unroll
        for (int mi = 0; mi < 8; mi++) {
#pragma unroll
            for (int r = 0; r < 4; r++) {
                int row = rowb + mi * 16 + r;
                float v = acc[mi][ni][r] + bv;
                if (MODE == 1) {
                    v += resid[(u64)row * N + col];
                    outF[(u64)row * N + col] = v;
                } else {
                    if (MODE == 2) v = 0.5f * v * (1.0f + erff(v * 0.70710678118654752f));
                    outB[(u64)row * N + col] = f2bf(v);
                }
            }
        }
    }
}

// ---------------------------------------------------------------------------
// Attention: one block per (b,h). S=64, DK=64. Q/K/V packed [8192][2304].
// ---------------------------------------------------------------------------
__global__ __launch_bounds__(256) void attn_kernel(
    const u16* __restrict__ QKV, const int* __restrict__ xids, u16* __restrict__ ctx)
{
    constexpr int LDA = 72;
    __shared__ __align__(16) u16 sQ[64 * LDA];
    __shared__ __align__(16) u16 sK[64 * LDA];
    __shared__ __align__(16) u16 sVt[64 * LDA];
    int tid = threadIdx.x;
    int lane = tid & 63, wave = tid >> 6;
    int b = blockIdx.x / 12, h = blockIdx.x % 12;
    {
        int r = tid >> 2, cb = (tid & 3) * 16;
        u64 gbase = ((u64)(b * 64 + r)) * 2304 + h * 64 + cb;
        uint4 q0 = *(const uint4*)(QKV + gbase);
        uint4 q1 = *(const uint4*)(QKV + gbase + 8);
        uint4 k0 = *(const uint4*)(QKV + gbase + 768);
        uint4 k1 = *(const uint4*)(QKV + gbase + 776);
        uint4 v0 = *(const uint4*)(QKV + gbase + 1536);
        uint4 v1 = *(const uint4*)(QKV + gbase + 1544);
        *(uint4*)(sQ + r * LDA + cb) = q0;
        *(uint4*)(sQ + r * LDA + cb + 8) = q1;
        *(uint4*)(sK + r * LDA + cb) = k0;
        *(uint4*)(sK + r * LDA + cb + 8) = k1;
        u16 vt[16];
        *(uint4*)(vt) = v0; *(uint4*)(vt + 8) = v1;
#pragma unroll
        for (int j = 0; j < 16; j++) sVt[(cb + j) * LDA + r] = vt[j];
    }
    __syncthreads();
    int cl = lane & 15, quad = lane >> 4;

    f32x4 sc[4];
    const f32x4 vz = {0.f, 0.f, 0.f, 0.f};
#pragma unroll
    for (int ni = 0; ni < 4; ni++) sc[ni] = vz;
#pragma unroll
    for (int kt = 0; kt < 2; kt++) {
        bf16x8 a = *(const bf16x8*)(sQ + (wave * 16 + cl) * LDA + kt * 32 + quad * 8);
#pragma unroll
        for (int ni = 0; ni < 4; ni++) {
            bf16x8 bb = *(const bf16x8*)(sK + (ni * 16 + cl) * LDA + kt * 32 + quad * 8);
            sc[ni] = __builtin_amdgcn_mfma_f32_16x16x32_bf16(a, bb, sc[ni], 0, 0, 0);
        }
    }
    bool ok[4];
#pragma unroll
    for (int ni = 0; ni < 4; ni++) ok[ni] = xids[b * 64 + ni * 16 + cl] > 0;
    float p[4][4];
#pragma unroll
    for (int r = 0; r < 4; r++) {
        float m = -3.0e38f;
#pragma unroll
        for (int ni = 0; ni < 4; ni++) {
            float s = ok[ni] ? sc[ni][r] * 0.125f : -1e9f;
            p[ni][r] = s;
            m = fmaxf(m, s);
        }
#pragma unroll
        for (int off = 1; off < 16; off <<= 1) m = fmaxf(m, __shfl_xor(m, off));
        float sum = 0.f;
#pragma unroll
        for (int ni = 0; ni < 4; ni++) { float e = __expf(p[ni][r] - m); p[ni][r] = e; sum += e; }
#pragma unroll
        for (int off = 1; off < 16; off <<= 1) sum += __shfl_xor(sum, off);
        float inv = 1.0f / sum;
#pragma unroll
        for (int ni = 0; ni < 4; ni++) p[ni][r] *= inv;
    }
    __syncthreads();
#pragma unroll
    for (int ni = 0; ni < 4; ni++)
#pragma unroll
        for (int r = 0; r < 4; r++)
            sQ[(wave * 16 + quad * 4 + r) * LDA + ni * 16 + cl] = f2bf(p[ni][r]);
    __syncthreads();
    f32x4 o[4];
#pragma unroll
    for (int ni = 0; ni < 4; ni++) o[ni] = vz;
#pragma unroll
    for (int kt = 0; kt < 2; kt++) {
        bf16x8 a = *(const bf16x8*)(sQ + (wave * 16 + cl) * LDA + kt * 32 + quad * 8);
#pragma unroll
        for (int ni = 0; ni < 4; ni++) {
            bf16x8 bb = *(const bf16x8*)(sVt + (ni * 16 + cl) * LDA + kt * 32 + quad * 8);
            o[ni] = __builtin_amdgcn_mfma_f32_16x16x32_bf16(a, bb, o[ni], 0, 0, 0);
        }
    }
#pragma unroll
    for (int ni = 0; ni < 4; ni++)
#pragma unroll
        for (int r = 0; r < 4; r++)
            ctx[((u64)(b * 64 + wave * 16 + quad * 4 + r)) * 768 + h * 64 + ni * 16 + cl] =
                f2bf(o[ni][r]);
}

// ---------------------------------------------------------------------------
// LayerNorm; outF may alias X (row read into regs first). Writes fp32
// (residual path) + bf16 (GEMM-A path). If isfinal, also writes d_out.
// ---------------------------------------------------------------------------
__global__ __launch_bounds__(256) void ln_kernel(
    const float* __restrict__ X, const void* __restrict__ g, const void* __restrict__ bta,
    const int* __restrict__ flagp, float* __restrict__ outF, u16* __restrict__ outH,
    void* __restrict__ outD, int isfinal, u64 oB)
{
    int isbf = *flagp;
    int t = blockIdx.x;
    const float* xr = X + (u64)t * 768;
    int tid = threadIdx.x;
    float v0 = xr[tid], v1 = xr[tid + 256], v2 = xr[tid + 512];
    float s = v0 + v1 + v2;
    float sq = v0 * v0 + v1 * v1 + v2 * v2;
#pragma unroll
    for (int off = 1; off < 64; off <<= 1) { s += __shfl_xor(s, off); sq += __shfl_xor(sq, off); }
    __shared__ float red[8];
    int lane = tid & 63, wave = tid >> 6;
    if (lane == 0) { red[wave] = s; red[4 + wave] = sq; }
    __syncthreads();
    s = red[0] + red[1] + red[2] + red[3];
    sq = red[4] + red[5] + red[6] + red[7];
    float mu = s * (1.0f / 768.0f);
    float var = sq * (1.0f / 768.0f) - mu * mu;
    float rs = rsqrtf(var + 1e-5f);
    float* of = outF + (u64)t * 768;
#pragma unroll
    for (int i = 0; i < 3; i++) {
        int c = tid + i * 256;
        float v = (i == 0) ? v0 : (i == 1) ? v1 : v2;
        float y = (v - mu) * rs * ldmix(g, oB + c, isbf) + ldmix(bta, oB + c, isbf);
        of[c] = y;
        outH[(u64)t * 768 + c] = f2bf(y);
        if (isfinal) {
            if (isbf) ((u16*)outD)[(u64)t * 768 + c] = f2bf(y);
            else      ((float*)outD)[(u64)t * 768 + c] = y;
        }
    }
}

// ---------------------------------------------------------------------------
extern "C" void kernel_launch(void* const* d_in, const int* in_sizes, int n_in,
                              void* d_out, int out_size, void* d_ws, size_t ws_size,
                              hipStream_t stream)
{
    const int* x    = (const int*)d_in[0];
    const int* seg  = (const int*)d_in[1];
    const void* tok = d_in[2];
    const void* sege= d_in[3];
    const void* Wq  = d_in[4];
    const void* bq  = d_in[5];
    const void* Wk  = d_in[6];
    const void* bk  = d_in[7];
    const void* Wv  = d_in[8];
    const void* bv  = d_in[9];
    const void* Wo  = d_in[10];
    const void* bo  = d_in[11];
    const void* lng = d_in[12];
    const void* lnb = d_in[13];
    const void* W1  = d_in[14];
    const void* b1  = d_in[15];
    const void* W2  = d_in[16];
    const void* b2  = d_in[17];

    const u64 ND = 8192ull * 768ull;
    char* p = (char*)d_ws;
    auto alloc = [&](size_t bytes) { char* q = p; p += (bytes + 255) & ~(size_t)255; return q; };
    int*   flag = (int*)alloc(256);
    float* hF   = (float*)alloc(ND * 4);
    float* xF   = (float*)alloc(ND * 4);
    u16*   hB   = (u16*)alloc(ND * 2);
    u16*   xB   = (u16*)alloc(ND * 2);
    u16*   qkvB = (u16*)alloc(ND * 3 * 2);   // [8192][2304]; ffB aliases qkv+ctx
    u16*   ctxB = (u16*)alloc(ND * 2);
    u16*   ffB  = qkvB;                       // 8192*3072*2 = qkv(3*ND*2)+ctx(ND*2)
    u16*   Wt   = (u16*)alloc(7077888ull * 2);

    detect_kernel<<<1, 64, 0, stream>>>((const unsigned*)tok, flag);
    embed_kernel<<<8192, 256, 0, stream>>>(x, seg, tok, sege, flag, hF, hB);

    dim3 gq(9, 32), gp(3, 32), gf1(12, 32), gf2(3, 32);
    for (int l = 0; l < 12; l++) {
        const u64 oS = (u64)l * 589824ull, oF = (u64)l * 2359296ull;
        const u64 oB = (u64)l * 768ull, oB1 = (u64)l * 3072ull;
        transpose6<<<6912, 256, 0, stream>>>(Wq, Wk, Wv, Wo, W1, W2, Wt, flag, oS, oF);
        // fused QKV: [8192,768] @ [2304,768]^T -> [8192,2304]
        gemm8p<3><<<gq, 512, 0, stream>>>(hB, Wt, bq, bk, bv, oB,
                                          nullptr, nullptr, qkvB, flag, 2304, 768);
        attn_kernel<<<1536, 256, 0, stream>>>(qkvB, x, ctxB);
        gemm8p<1><<<gp, 512, 0, stream>>>(ctxB, Wt + 1769472, bo, nullptr, nullptr, oB,
                                          hF, xF, nullptr, flag, 768, 768);
        ln_kernel<<<8192, 256, 0, stream>>>(xF, lng, lnb, flag, xF, xB, nullptr, 0, oB);
        gemm8p<2><<<gf1, 512, 0, stream>>>(xB, Wt + 2359296, b1, nullptr, nullptr, oB1,
                                           nullptr, nullptr, ffB, flag, 3072, 768);
        gemm8p<1><<<gf2, 512, 0, stream>>>(ffB, Wt + 4718592, b2, nullptr, nullptr, oB,
                                           xF, xF, nullptr, flag, 768, 3072);
        ln_kernel<<<8192, 256, 0, stream>>>(xF, lng, lnb, flag, hF, hB,
                                            (l == 11) ? d_out : nullptr,
                                            (l == 11) ? 1 : 0, oB);
    }
}

// Round 3
// 3437.860 us; speedup vs baseline: 1.2399x; 1.2399x over previous
//
#include <hip/hip_runtime.h>
#include <math.h>

typedef unsigned short u16;
typedef __bf16 bf16x8 __attribute__((ext_vector_type(8)));
typedef float f32x4 __attribute__((ext_vector_type(4)));
typedef unsigned long long u64;

__device__ __forceinline__ float bf2f(u16 u) {
    union { unsigned u32; float f; } c; c.u32 = ((unsigned)u) << 16; return c.f;
}
__device__ __forceinline__ u16 f2bf(float f) {
    unsigned u = __float_as_uint(f);
    unsigned r = u + 0x7fff + ((u >> 16) & 1);
    return (u16)(r >> 16);
}
// element i of a float tensor whose dtype (bf16 vs fp32) is runtime-detected
__device__ __forceinline__ float ldmix(const void* p, u64 i, int isbf) {
    return isbf ? bf2f(((const u16*)p)[i]) : ((const float*)p)[i];
}
// async global->LDS, 16B per lane. LDS dest is wave-uniform base + lane*16.
__device__ __forceinline__ void gll16(const u16* g, u16* l) {
    __builtin_amdgcn_global_load_lds(
        (const __attribute__((address_space(1))) void*)g,
        (__attribute__((address_space(3))) void*)l, 16, 0, 0);
}

// ---------------------------------------------------------------------------
// Dtype probe: sample 64 words of tok_emb (nonzero rows). If low-16 bits look
// like bf16 N(0,0.02) values (exp field in [100,126]) for >=40/64 lanes,
// inputs are bf16. fp32 mantissa bits hit that window only ~10% of the time.
// ---------------------------------------------------------------------------
__global__ void detect_kernel(const unsigned* __restrict__ tokw, int* __restrict__ flag)
{
    int i = threadIdx.x;  // 0..63
    unsigned w = tokw[768 + i];
    unsigned e = (w >> 7) & 0xFF;
    bool hit = (e >= 100) && (e <= 126) && ((w & 0x7FFFu) != 0);
    unsigned long long m = __ballot(hit);
    if (i == 0) flag[0] = (__popcll(m) >= 40) ? 1 : 0;
}

// ---------------------------------------------------------------------------
// Embedding: h = tok_emb[x] + seg_emb[segment] + PE (computed on device)
// Writes fp32 (residual path) AND bf16 (GEMM-A path).
// ---------------------------------------------------------------------------
__global__ __launch_bounds__(256) void embed_kernel(
    const int* __restrict__ x, const int* __restrict__ seg,
    const void* __restrict__ tok, const void* __restrict__ se,
    const int* __restrict__ flagp, float* __restrict__ hF, u16* __restrict__ hB)
{
    int isbf = *flagp;
    int t = blockIdx.x;
    int pos = t & 63;
    int tokid = x[t], sgid = seg[t];
    int tid = threadIdx.x;
#pragma unroll
    for (int i = 0; i < 3; i++) {
        int d = tid + i * 256;
        int p = d >> 1;
        float freq = powf(10000.0f, (float)p * (1.0f / 192.0f));
        float arg = (float)pos / freq;
        float pe = (d & 1) ? cosf(arg) : sinf(arg);
        float v = ldmix(tok, (u64)tokid * 768 + d, isbf)
                + ldmix(se, (u64)sgid * 768 + d, isbf) + pe;
        hF[(u64)t * 768 + d] = v;
        hB[(u64)t * 768 + d] = f2bf(v);
    }
}

// ---------------------------------------------------------------------------
// Transpose+stage layer l's 6 weight matrices to bf16 [N][K] layout.
// ---------------------------------------------------------------------------
__global__ __launch_bounds__(256) void transpose6(
    const void* __restrict__ wq, const void* __restrict__ wk,
    const void* __restrict__ wv, const void* __restrict__ wo,
    const void* __restrict__ w1, const void* __restrict__ w2,
    u16* __restrict__ out, const int* __restrict__ flagp, u64 oS, u64 oF)
{
    int isbf = *flagp;
    int id = blockIdx.x;
    const void* src; u16* dst; int R, C; u64 off;
    if (id < 2304) {
        int m = id / 576; id -= m * 576; R = 768; C = 768; off = oS;
        src = (m == 0) ? wq : (m == 1) ? wk : (m == 2) ? wv : wo;
        dst = out + (u64)m * 589824;
    } else if (id < 4608) {
        id -= 2304; R = 768; C = 3072; off = oF; src = w1; dst = out + 2359296;
    } else {
        id -= 4608; R = 3072; C = 768; off = oF; src = w2; dst = out + 4718592;
    }
    int tilesC = C >> 5;
    int tr = id / tilesC, tc = id % tilesC;
    __shared__ float tile[32][33];
    int rl = threadIdx.x >> 5, cl = threadIdx.x & 31;
#pragma unroll
    for (int i = 0; i < 4; i++)
        tile[rl + 8 * i][cl] = ldmix(src, off + (u64)(tr * 32 + rl + 8 * i) * C + tc * 32 + cl, isbf);
    __syncthreads();
#pragma unroll
    for (int i = 0; i < 4; i++)
        dst[(u64)(tc * 32 + rl + 8 * i) * R + tr * 32 + cl] = f2bf(tile[cl][rl + 8 * i]);
}

// ---------------------------------------------------------------------------
// bf16 MFMA GEMM (m97 2-barrier structure, verified in r1):
//   C[M,N] = A[M,K] @ Bt[N,K]^T + bias
// r3 changes vs r1 (no sync-structure change):
//  - zero-conflict LDS chunk swizzle (r2-measured 0 conflicts): LDS 16B-chunk
//    (row, slot) holds global col-chunk slot^((row>>1)&3); inverse applied to
//    the global source address (LDS dest stays linear for global_load_lds).
//  - __launch_bounds__(256,4): 4 blocks/CU residency to hide barrier drains.
//  - grouped block mapping (GROUP_M=8) for per-XCD L2 panel reuse.
// MODE 1: outF = acc+bias+resid (fp32, may alias resid)
// MODE 2: outB = gelu(acc+bias) (bf16)
// MODE 3: fused QKV - bias from {bA,bB,bC} by 128-col tile group (bf16 out)
// ---------------------------------------------------------------------------
template <int MODE>
__global__ __launch_bounds__(256, 4) void gemm_bt(
    const u16* __restrict__ A, const u16* __restrict__ Bt,
    const void* __restrict__ bA, const void* __restrict__ bB,
    const void* __restrict__ bC, u64 oB, const float* __restrict__ resid,
    float* __restrict__ outF, u16* __restrict__ outB,
    const int* __restrict__ flagp, int N, int K)
{
    __shared__ __align__(16) u16 sA[128 * 32];
    __shared__ __align__(16) u16 sB[128 * 32];
    int tid = threadIdx.x;
    int lane = tid & 63, wave = tid >> 6;
    int wr = wave >> 1, wc = wave & 1;
    int cl = lane & 15, quad = lane >> 4;

    // grouped block mapping (gridDim.y == 64 for all call sites, % 8 == 0)
    int lin = blockIdx.y * gridDim.x + blockIdx.x;
    int per = gridDim.x << 3;
    int grp = lin / per, rem = lin - grp * per;
    int bm = (grp << 3) + (rem & 7), bn = rem >> 3;

    // stage-side sources: LDS chunk c={row=c>>2, slot=c&3} is filled from
    // global col-chunk g = slot ^ ((row>>1)&3)
    const u16 *As0, *As1, *Bs0, *Bs1;
    {
        int c0 = tid, c1 = 256 + tid;
        int r0 = c0 >> 2, g0 = ((c0 & 3) ^ ((r0 >> 1) & 3)) << 3;
        int r1 = c1 >> 2, g1 = ((c1 & 3) ^ ((r1 >> 1) & 3)) << 3;
        As0 = A  + (u64)(bm * 128 + r0) * K + g0;
        As1 = A  + (u64)(bm * 128 + r1) * K + g1;
        Bs0 = Bt + (u64)(bn * 128 + r0) * K + g0;
        Bs1 = Bt + (u64)(bn * 128 + r1) * K + g1;
    }
    u16* dA0 = sA + wave * 512;  u16* dA1 = sA + 2048 + wave * 512;
    u16* dB0 = sB + wave * 512;  u16* dB1 = sB + 2048 + wave * 512;

    // read-side swizzle: (row>>1)&3 == (cl>>1)&3 for all fragment rows
    const int swz = (quad ^ ((cl >> 1) & 3)) << 3;

    f32x4 acc[4][4];
    const f32x4 vz = {0.f, 0.f, 0.f, 0.f};
#pragma unroll
    for (int mi = 0; mi < 4; mi++)
#pragma unroll
        for (int ni = 0; ni < 4; ni++) acc[mi][ni] = vz;

    // prologue: stage tile 0
    gll16(As0, dA0); gll16(As1, dA1);
    gll16(Bs0, dB0); gll16(Bs1, dB1);

    for (int k0 = 0; k0 < K; k0 += 32) {
        __syncthreads();   // drains vmcnt(0): tile k resident in LDS
        bf16x8 af[4], bfr[4];
#pragma unroll
        for (int mi = 0; mi < 4; mi++)
            af[mi] = *(const bf16x8*)(sA + (wr * 64 + mi * 16 + cl) * 32 + swz);
#pragma unroll
        for (int ni = 0; ni < 4; ni++)
            bfr[ni] = *(const bf16x8*)(sB + (wc * 64 + ni * 16 + cl) * 32 + swz);
        __syncthreads();   // lgkm drained per-wave before barrier: reads done
        int kn = k0 + 32;
        if (kn < K) {      // stage tile k+1; flies under the MFMAs below
            gll16(As0 + kn, dA0); gll16(As1 + kn, dA1);
            gll16(Bs0 + kn, dB0); gll16(Bs1 + kn, dB1);
        }
#pragma unroll
        for (int mi = 0; mi < 4; mi++)
#pragma unroll
            for (int ni = 0; ni < 4; ni++)
                acc[mi][ni] = __builtin_amdgcn_mfma_f32_16x16x32_bf16(
                    af[mi], bfr[ni], acc[mi][ni], 0, 0, 0);
    }

    int isbf = *flagp;
    int rowb = bm * 128 + wr * 64 + quad * 4;   // C/D: col=lane&15, row=quad*4+reg
    int colb = bn * 128 + wc * 64 + cl;
    const void* bp = bA;
    int csub = 0;
    if (MODE == 3) {       // 18 col-tiles of 128: 0-5 Q, 6-11 K, 12-17 V
        int ms = bn / 6;
        bp = (ms == 0) ? bA : (ms == 1) ? bB : bC;
        csub = ms * 768;
    }
#pragma unroll
    for (int ni = 0; ni < 4; ni++) {
        int col = colb + ni * 16;
        float bv = ldmix(bp, oB + (u64)(col - csub), isbf);
#pragma unroll
        for (int mi = 0; mi < 4; mi++) {
#pragma unroll
            for (int r = 0; r < 4; r++) {
                int row = rowb + mi * 16 + r;
                float v = acc[mi][ni][r] + bv;
                if (MODE == 1) {
                    v += resid[(u64)row * N + col];
                    outF[(u64)row * N + col] = v;
                } else {
                    if (MODE == 2) v = 0.5f * v * (1.0f + erff(v * 0.70710678118654752f));
                    outB[(u64)row * N + col] = f2bf(v);
                }
            }
        }
    }
}

// ---------------------------------------------------------------------------
// Attention: one block per (b,h). S=64, DK=64. Q/K/V packed [8192][2304].
// ---------------------------------------------------------------------------
__global__ __launch_bounds__(256) void attn_kernel(
    const u16* __restrict__ QKV, const int* __restrict__ xids, u16* __restrict__ ctx)
{
    constexpr int LDA = 72;
    __shared__ __align__(16) u16 sQ[64 * LDA];
    __shared__ __align__(16) u16 sK[64 * LDA];
    __shared__ __align__(16) u16 sVt[64 * LDA];
    int tid = threadIdx.x;
    int lane = tid & 63, wave = tid >> 6;
    int b = blockIdx.x / 12, h = blockIdx.x % 12;
    {
        int r = tid >> 2, cb = (tid & 3) * 16;
        u64 gbase = ((u64)(b * 64 + r)) * 2304 + h * 64 + cb;
        uint4 q0 = *(const uint4*)(QKV + gbase);
        uint4 q1 = *(const uint4*)(QKV + gbase + 8);
        uint4 k0 = *(const uint4*)(QKV + gbase + 768);
        uint4 k1 = *(const uint4*)(QKV + gbase + 776);
        uint4 v0 = *(const uint4*)(QKV + gbase + 1536);
        uint4 v1 = *(const uint4*)(QKV + gbase + 1544);
        *(uint4*)(sQ + r * LDA + cb) = q0;
        *(uint4*)(sQ + r * LDA + cb + 8) = q1;
        *(uint4*)(sK + r * LDA + cb) = k0;
        *(uint4*)(sK + r * LDA + cb + 8) = k1;
        u16 vt[16];
        *(uint4*)(vt) = v0; *(uint4*)(vt + 8) = v1;
#pragma unroll
        for (int j = 0; j < 16; j++) sVt[(cb + j) * LDA + r] = vt[j];
    }
    __syncthreads();
    int cl = lane & 15, quad = lane >> 4;

    f32x4 sc[4];
    const f32x4 vz = {0.f, 0.f, 0.f, 0.f};
#pragma unroll
    for (int ni = 0; ni < 4; ni++) sc[ni] = vz;
#pragma unroll
    for (int kt = 0; kt < 2; kt++) {
        bf16x8 a = *(const bf16x8*)(sQ + (wave * 16 + cl) * LDA + kt * 32 + quad * 8);
#pragma unroll
        for (int ni = 0; ni < 4; ni++) {
            bf16x8 bb = *(const bf16x8*)(sK + (ni * 16 + cl) * LDA + kt * 32 + quad * 8);
            sc[ni] = __builtin_amdgcn_mfma_f32_16x16x32_bf16(a, bb, sc[ni], 0, 0, 0);
        }
    }
    bool ok[4];
#pragma unroll
    for (int ni = 0; ni < 4; ni++) ok[ni] = xids[b * 64 + ni * 16 + cl] > 0;
    float p[4][4];
#pragma unroll
    for (int r = 0; r < 4; r++) {
        float m = -3.0e38f;
#pragma unroll
        for (int ni = 0; ni < 4; ni++) {
            float s = ok[ni] ? sc[ni][r] * 0.125f : -1e9f;
            p[ni][r] = s;
            m = fmaxf(m, s);
        }
#pragma unroll
        for (int off = 1; off < 16; off <<= 1) m = fmaxf(m, __shfl_xor(m, off));
        float sum = 0.f;
#pragma unroll
        for (int ni = 0; ni < 4; ni++) { float e = __expf(p[ni][r] - m); p[ni][r] = e; sum += e; }
#pragma unroll
        for (int off = 1; off < 16; off <<= 1) sum += __shfl_xor(sum, off);
        float inv = 1.0f / sum;
#pragma unroll
        for (int ni = 0; ni < 4; ni++) p[ni][r] *= inv;
    }
    __syncthreads();
#pragma unroll
    for (int ni = 0; ni < 4; ni++)
#pragma unroll
        for (int r = 0; r < 4; r++)
            sQ[(wave * 16 + quad * 4 + r) * LDA + ni * 16 + cl] = f2bf(p[ni][r]);
    __syncthreads();
    f32x4 o[4];
#pragma unroll
    for (int ni = 0; ni < 4; ni++) o[ni] = vz;
#pragma unroll
    for (int kt = 0; kt < 2; kt++) {
        bf16x8 a = *(const bf16x8*)(sQ + (wave * 16 + cl) * LDA + kt * 32 + quad * 8);
#pragma unroll
        for (int ni = 0; ni < 4; ni++) {
            bf16x8 bb = *(const bf16x8*)(sVt + (ni * 16 + cl) * LDA + kt * 32 + quad * 8);
            o[ni] = __builtin_amdgcn_mfma_f32_16x16x32_bf16(a, bb, o[ni], 0, 0, 0);
        }
    }
#pragma unroll
    for (int ni = 0; ni < 4; ni++)
#pragma unroll
        for (int r = 0; r < 4; r++)
            ctx[((u64)(b * 64 + wave * 16 + quad * 4 + r)) * 768 + h * 64 + ni * 16 + cl] =
                f2bf(o[ni][r]);
}

// ---------------------------------------------------------------------------
// LayerNorm; outF may alias X (row read into regs first). Writes fp32
// (residual path) + bf16 (GEMM-A path). If isfinal, also writes d_out.
// ---------------------------------------------------------------------------
__global__ __launch_bounds__(256) void ln_kernel(
    const float* __restrict__ X, const void* __restrict__ g, const void* __restrict__ bta,
    const int* __restrict__ flagp, float* __restrict__ outF, u16* __restrict__ outH,
    void* __restrict__ outD, int isfinal, u64 oB)
{
    int isbf = *flagp;
    int t = blockIdx.x;
    const float* xr = X + (u64)t * 768;
    int tid = threadIdx.x;
    float v0 = xr[tid], v1 = xr[tid + 256], v2 = xr[tid + 512];
    float s = v0 + v1 + v2;
    float sq = v0 * v0 + v1 * v1 + v2 * v2;
#pragma unroll
    for (int off = 1; off < 64; off <<= 1) { s += __shfl_xor(s, off); sq += __shfl_xor(sq, off); }
    __shared__ float red[8];
    int lane = tid & 63, wave = tid >> 6;
    if (lane == 0) { red[wave] = s; red[4 + wave] = sq; }
    __syncthreads();
    s = red[0] + red[1] + red[2] + red[3];
    sq = red[4] + red[5] + red[6] + red[7];
    float mu = s * (1.0f / 768.0f);
    float var = sq * (1.0f / 768.0f) - mu * mu;
    float rs = rsqrtf(var + 1e-5f);
    float* of = outF + (u64)t * 768;
#pragma unroll
    for (int i = 0; i < 3; i++) {
        int c = tid + i * 256;
        float v = (i == 0) ? v0 : (i == 1) ? v1 : v2;
        float y = (v - mu) * rs * ldmix(g, oB + c, isbf) + ldmix(bta, oB + c, isbf);
        of[c] = y;
        outH[(u64)t * 768 + c] = f2bf(y);
        if (isfinal) {
            if (isbf) ((u16*)outD)[(u64)t * 768 + c] = f2bf(y);
            else      ((float*)outD)[(u64)t * 768 + c] = y;
        }
    }
}

// ---------------------------------------------------------------------------
extern "C" void kernel_launch(void* const* d_in, const int* in_sizes, int n_in,
                              void* d_out, int out_size, void* d_ws, size_t ws_size,
                              hipStream_t stream)
{
    const int* x    = (const int*)d_in[0];
    const int* seg  = (const int*)d_in[1];
    const void* tok = d_in[2];
    const void* sege= d_in[3];
    const void* Wq  = d_in[4];
    const void* bq  = d_in[5];
    const void* Wk  = d_in[6];
    const void* bk  = d_in[7];
    const void* Wv  = d_in[8];
    const void* bv  = d_in[9];
    const void* Wo  = d_in[10];
    const void* bo  = d_in[11];
    const void* lng = d_in[12];
    const void* lnb = d_in[13];
    const void* W1  = d_in[14];
    const void* b1  = d_in[15];
    const void* W2  = d_in[16];
    const void* b2  = d_in[17];

    const u64 ND = 8192ull * 768ull;
    char* p = (char*)d_ws;
    auto alloc = [&](size_t bytes) { char* q = p; p += (bytes + 255) & ~(size_t)255; return q; };
    int*   flag = (int*)alloc(256);
    float* hF   = (float*)alloc(ND * 4);
    float* xF   = (float*)alloc(ND * 4);
    u16*   hB   = (u16*)alloc(ND * 2);
    u16*   xB   = (u16*)alloc(ND * 2);
    u16*   qkvB = (u16*)alloc(ND * 3 * 2);   // [8192][2304]; ffB aliases qkv+ctx
    u16*   ctxB = (u16*)alloc(ND * 2);
    u16*   ffB  = qkvB;                       // 8192*3072*2 = qkv(3*ND*2)+ctx(ND*2)
    u16*   Wt   = (u16*)alloc(7077888ull * 2);

    detect_kernel<<<1, 64, 0, stream>>>((const unsigned*)tok, flag);
    embed_kernel<<<8192, 256, 0, stream>>>(x, seg, tok, sege, flag, hF, hB);

    dim3 g768(6, 64), g2304(18, 64), g3072(24, 64);
    for (int l = 0; l < 12; l++) {
        const u64 oS = (u64)l * 589824ull, oF = (u64)l * 2359296ull;
        const u64 oB = (u64)l * 768ull, oB1 = (u64)l * 3072ull;
        transpose6<<<6912, 256, 0, stream>>>(Wq, Wk, Wv, Wo, W1, W2, Wt, flag, oS, oF);
        // fused QKV: [8192,768] @ [2304,768]^T -> [8192,2304]
        gemm_bt<3><<<g2304, 256, 0, stream>>>(hB, Wt, bq, bk, bv, oB,
                                              nullptr, nullptr, qkvB, flag, 2304, 768);
        attn_kernel<<<1536, 256, 0, stream>>>(qkvB, x, ctxB);
        gemm_bt<1><<<g768, 256, 0, stream>>>(ctxB, Wt + 1769472, bo, nullptr, nullptr, oB,
                                             hF, xF, nullptr, flag, 768, 768);
        ln_kernel<<<8192, 256, 0, stream>>>(xF, lng, lnb, flag, xF, xB, nullptr, 0, oB);
        gemm_bt<2><<<g3072, 256, 0, stream>>>(xB, Wt + 2359296, b1, nullptr, nullptr, oB1,
                                              nullptr, nullptr, ffB, flag, 3072, 768);
        gemm_bt<1><<<g768, 256, 0, stream>>>(ffB, Wt + 4718592, b2, nullptr, nullptr, oB,
                                             xF, xF, nullptr, flag, 768, 3072);
        ln_kernel<<<8192, 256, 0, stream>>>(xF, lng, lnb, flag, hF, hB,
                                            (l == 11) ? d_out : nullptr,
                                            (l == 11) ? 1 : 0, oB);
    }
}